// Round 2
// baseline (1228.932 us; speedup 1.0000x reference)
//
#include <hip/hip_runtime.h>
#include <math.h>

#define NATOM 100000
#define MNBR 12
#define FDIM 128
#define NFDIM 64

typedef __attribute__((ext_vector_type(8))) short bf16x8;
typedef __attribute__((ext_vector_type(4))) float f32x4;

__device__ inline unsigned short f2bf(float x) {
    union { float f; unsigned u; } v; v.f = x;
    unsigned r = v.u + 0x7FFFu + ((v.u >> 16) & 1u);   // RNE
    return (unsigned short)(r >> 16);
}

__device__ inline void st4bf(short* p, float4 x) {
    unsigned lo = (unsigned)f2bf(x.x) | ((unsigned)f2bf(x.y) << 16);
    unsigned hi = (unsigned)f2bf(x.z) | ((unsigned)f2bf(x.w) << 16);
    *(uint2*)p = make_uint2(lo, hi);
}

// ---------------------------------------------------------------------------
// K0: pack Wq|Wk|Wv (pk1) and Wn (pk2) into bf16 B-fragment order.
// B-frag (16x16x32): lane holds B[k = (lane>>4)*8 + j][n = lane&15].
// pk short index = ((fragId*ksteps + s)*64 + lane)*8 + j.
// ---------------------------------------------------------------------------
__global__ __launch_bounds__(256) void pack_weights(
    const float* __restrict__ Wq, const float* __restrict__ Wk,
    const float* __restrict__ Wv, const float* __restrict__ Wn,
    short* __restrict__ pk1, short* __restrict__ pk2)
{
    int g = blockIdx.x * 256 + threadIdx.x;
    if (g < 3 * 128 * 128) {
        int fe = g >> 9;            // f*4 + s
        int r = g & 511;
        int lane = r >> 3, jj = r & 7;
        int s = fe & 3, f = fe >> 2;
        int ct = f & 7, mt = f >> 3;
        int k = s * 32 + (lane >> 4) * 8 + jj;
        int n = ct * 16 + (lane & 15);
        const float* W = (mt == 0) ? Wq : ((mt == 1) ? Wk : Wv);
        pk1[g] = (short)f2bf(W[k * 128 + n]);
    } else {
        int g2 = g - 49152;         // 16*512 = 8192 shorts for Wn
        int fe = g2 >> 9;           // ct*2 + s
        int r = g2 & 511;
        int lane = r >> 3, jj = r & 7;
        int s = fe & 1, ct = fe >> 1;
        int k = s * 32 + (lane >> 4) * 8 + jj;
        int n = ct * 16 + (lane & 15);
        pk2[g2] = (short)f2bf(Wn[k * 128 + n]);
    }
}

// ---------------------------------------------------------------------------
// K1: QKV projection via MFMA. 64 atoms/block, 4 waves; wave w = row-tile w.
// 24 col-tiles (q|k|v x 8), K = 4 steps of 32. A bf16 in LDS (stride 136).
// ---------------------------------------------------------------------------
__global__ __launch_bounds__(256) void qkv_mfma(
    const float* __restrict__ atom_fea,
    const short* __restrict__ pk1,
    const float* __restrict__ bq, const float* __restrict__ bk,
    const float* __restrict__ bv,
    float* __restrict__ q, float* __restrict__ k, float* __restrict__ v)
{
    __shared__ short s_a[64 * 136];   // 17408 B, 2-way bank aliasing (free)
    const int tid = threadIdx.x;
    const int base = blockIdx.x * 64;
#pragma unroll
    for (int e = 0; e < 8; ++e) {
        int f4 = e * 256 + tid;          // float4 index in 64x128 tile
        int row = f4 >> 5, c4 = f4 & 31;
        int atom = base + row;
        float4 x = make_float4(0.f, 0.f, 0.f, 0.f);
        if (atom < NATOM) x = *(const float4*)(atom_fea + (size_t)atom * 128 + c4 * 4);
        st4bf(&s_a[row * 136 + c4 * 4], x);
    }
    __syncthreads();

    const int lane = tid & 63, w = tid >> 6;
    const int quad = lane >> 4, j16 = lane & 15;

    f32x4 acc[24];
#pragma unroll
    for (int i = 0; i < 24; ++i) acc[i] = (f32x4){0.f, 0.f, 0.f, 0.f};

    const short* arow = &s_a[(w * 16 + j16) * 136];
#pragma unroll
    for (int s = 0; s < 4; ++s) {
        bf16x8 af = *(const bf16x8*)(arow + s * 32 + quad * 8);
#pragma unroll
        for (int f = 0; f < 24; ++f) {
            bf16x8 bfr = *(const bf16x8*)(pk1 + (((f * 4 + s) * 64 + lane) << 3));
            acc[f] = __builtin_amdgcn_mfma_f32_16x16x32_bf16(af, bfr, acc[f], 0, 0, 0);
        }
    }

    float* outs[3] = {q, k, v};
    const float* biases[3] = {bq, bk, bv};
#pragma unroll
    for (int f = 0; f < 24; ++f) {
        const int mt = f >> 3, ct = f & 7;
        const int col = ct * 16 + j16;
        const float b = biases[mt][col];
        float* op = outs[mt];
#pragma unroll
        for (int r = 0; r < 4; ++r) {
            int atom = base + w * 16 + quad * 4 + r;
            if (atom < NATOM) op[(size_t)atom * 128 + col] = acc[f][r] + b;
        }
    }
}

// ---------------------------------------------------------------------------
// K2: fused neighbor projection (MFMA) + gather + attention.
// 8 atoms/block; M padded 12->16 so each 16-row tile = one atom.
// Wave w owns heads {2w, 2w+1} for all 8 atoms (32 MFMAs).
// C-layout: col j16 = feature within head, row = quad*4+reg = neighbor m
// (quad 3 = pad rows, masked out of softmax). att overwrites q buffer.
// ---------------------------------------------------------------------------
__global__ __launch_bounds__(256) void attn_mfma(
    const float* __restrict__ nbr_fea,
    const int*   __restrict__ nbr_idx,
    const short* __restrict__ pk2,
    const float* __restrict__ bn,
    float* qatt,
    const float* __restrict__ kbuf,
    const float* __restrict__ vbuf)
{
    __shared__ short s_a[8 * 16 * 72];   // 18432 B, stride 72 shorts
    const int tid = threadIdx.x;
    const long long blk = blockIdx.x;

    const float* gsrc = nbr_fea + blk * 6144;
#pragma unroll
    for (int e = 0; e < 6; ++e) {
        int f4 = e * 256 + tid;           // [0,1536) float4s = 96 rows x 16
        int r = f4 >> 4, c4 = f4 & 15;
        int a = r / 12, m = r - a * 12;
        float4 x = *(const float4*)(gsrc + (size_t)f4 * 4);
        st4bf(&s_a[(a * 16 + m) * 72 + c4 * 4], x);
    }
    {   // zero the 4 pad rows per atom: 32 rows x 128B = 256 x 16B chunks
        int prow = tid >> 3, c = tid & 7;
        int a = prow >> 2, m = 12 + (prow & 3);
        *(uint4*)&s_a[(a * 16 + m) * 72 + c * 8] = make_uint4(0, 0, 0, 0);
    }
    __syncthreads();

    const int lane = tid & 63, w = tid >> 6;
    const int quad = lane >> 4, j16 = lane & 15;

    bf16x8 bfr[2][2];                     // [hh][kstep], reused for 8 atoms
#pragma unroll
    for (int hh = 0; hh < 2; ++hh)
#pragma unroll
        for (int s = 0; s < 2; ++s) {
            int ct = w * 2 + hh;
            bfr[hh][s] = *(const bf16x8*)(pk2 + (((ct * 2 + s) * 64 + lane) << 3));
        }

    f32x4 acc[8][2];
#pragma unroll
    for (int a = 0; a < 8; ++a) {
        acc[a][0] = (f32x4){0.f, 0.f, 0.f, 0.f};
        acc[a][1] = (f32x4){0.f, 0.f, 0.f, 0.f};
    }

#pragma unroll
    for (int s = 0; s < 2; ++s) {
#pragma unroll
        for (int a = 0; a < 8; ++a) {
            bf16x8 af = *(const bf16x8*)&s_a[(a * 16 + j16) * 72 + s * 32 + quad * 8];
            acc[a][0] = __builtin_amdgcn_mfma_f32_16x16x32_bf16(af, bfr[0][s], acc[a][0], 0, 0, 0);
            acc[a][1] = __builtin_amdgcn_mfma_f32_16x16x32_bf16(af, bfr[1][s], acc[a][1], 0, 0, 0);
        }
    }

    const float bnc0 = bn[w * 32 + j16];
    const float bnc1 = bn[w * 32 + 16 + j16];
    const bool valid = (quad < 3);        // quad 3 = pad rows m 12..15

#pragma unroll 2
    for (int a = 0; a < 8; ++a) {
        const long long n = blk * 8 + a;
        int nidx[4];
#pragma unroll
        for (int r = 0; r < 4; ++r)
            nidx[r] = valid ? nbr_idx[n * 12 + quad * 4 + r] : 0;
#pragma unroll
        for (int hh = 0; hh < 2; ++hh) {
            const int col = w * 32 + hh * 16 + j16;
            const float bnc = hh ? bnc1 : bnc0;
            float qv = qatt[n * 128 + col];
            f32x4 t = acc[a][hh];
            float sc[4], nv[4];
#pragma unroll
            for (int r = 0; r < 4; ++r) {
                float tm = t[r] + bnc;                 // nbr_t + bn
                int off = nidx[r] * 128 + col;
                float nk = kbuf[off] + tm;
                nv[r] = vbuf[off] + tm;
                float p = qv * nk;
                p += __shfl_xor(p, 1, 16);
                p += __shfl_xor(p, 2, 16);
                p += __shfl_xor(p, 4, 16);
                p += __shfl_xor(p, 8, 16);
                sc[r] = p * 0.25f;                     // 1/sqrt(16)
            }
            float mx = valid ? fmaxf(fmaxf(sc[0], sc[1]), fmaxf(sc[2], sc[3]))
                             : -1e30f;
            mx = fmaxf(mx, __shfl_xor(mx, 16));
            mx = fmaxf(mx, __shfl_xor(mx, 32));
            float es = 0.f, av = 0.f;
            if (valid) {
#pragma unroll
                for (int r = 0; r < 4; ++r) {
                    float e = __expf(sc[r] - mx);
                    es += e;
                    av += e * nv[r];
                }
            }
            es += __shfl_xor(es, 16); es += __shfl_xor(es, 32);
            av += __shfl_xor(av, 16); av += __shfl_xor(av, 32);
            if (quad == 0) qatt[n * 128 + col] = av / es;
        }
    }
}

// ---------------------------------------------------------------------------
// K3: out projection + sigmoid gate + residual + LayerNorm (fp32, unchanged).
// ---------------------------------------------------------------------------
__global__ __launch_bounds__(256) void out_kernel(
    const float* __restrict__ attb, const float* __restrict__ atom_fea,
    const float* __restrict__ Wo, const float* __restrict__ bo,
    const float* __restrict__ Wg, const float* __restrict__ bg,
    const float* __restrict__ gamma, const float* __restrict__ beta,
    float* __restrict__ out)
{
    __shared__ float s_att[16 * 128];
    __shared__ float s_res[16 * 128];
    __shared__ float s_gate[16];
    __shared__ float s_mu[16], s_rs[16];
    const int tid = threadIdx.x;
    const long long base = (long long)blockIdx.x * (16 * 128);
#pragma unroll
    for (int t = 0; t < 8; ++t) {
        s_att[tid + t * 256] = attb[base + tid + t * 256];
        s_res[tid + t * 256] = atom_fea[base + tid + t * 256];
    }
    __syncthreads();

    const int j = tid & 127;
    const int half = tid >> 7;
    float acc[8];
#pragma unroll
    for (int a = 0; a < 8; ++a) acc[a] = 0.f;

    const float* srow = s_att + half * (8 * 128);
    for (int i = 0; i < 128; i += 4) {
        float wo[4];
#pragma unroll
        for (int ii = 0; ii < 4; ++ii) wo[ii] = Wo[(i + ii) * 128 + j];
#pragma unroll
        for (int a = 0; a < 8; ++a) {
            float4 x = *(const float4*)(srow + a * 128 + i);
            acc[a] += x.x * wo[0] + x.y * wo[1] + x.z * wo[2] + x.w * wo[3];
        }
    }
    const float boj = bo[j];
#pragma unroll
    for (int a = 0; a < 8; ++a) acc[a] += boj;
    __syncthreads();
#pragma unroll
    for (int a = 0; a < 8; ++a)
        s_att[(half * 8 + a) * 128 + j] = acc[a];
    __syncthreads();

    const int g = tid >> 4;
    const int r = tid & 15;
    float p = 0.f;
#pragma unroll
    for (int tt = 0; tt < 8; ++tt) {
        int jj = r + tt * 16;
        p += s_att[g * 128 + jj] * Wg[jj] + s_res[g * 128 + jj] * Wg[128 + jj];
    }
    p += __shfl_xor(p, 1, 16);
    p += __shfl_xor(p, 2, 16);
    p += __shfl_xor(p, 4, 16);
    p += __shfl_xor(p, 8, 16);
    if (r == 0) s_gate[g] = 1.f / (1.f + __expf(-(p + bg[0])));
    __syncthreads();

#pragma unroll
    for (int a = 0; a < 8; ++a) {
        int aa = half * 8 + a;
        float gt = s_gate[aa];
        float gv = gt * acc[a] + (1.f - gt) * s_res[aa * 128 + j];
        s_res[aa * 128 + j] = gv;
    }
    __syncthreads();

    float s1 = 0.f, s2 = 0.f;
#pragma unroll
    for (int tt = 0; tt < 8; ++tt) {
        float x = s_res[g * 128 + r + tt * 16];
        s1 += x; s2 += x * x;
    }
    s1 += __shfl_xor(s1, 1, 16); s2 += __shfl_xor(s2, 1, 16);
    s1 += __shfl_xor(s1, 2, 16); s2 += __shfl_xor(s2, 2, 16);
    s1 += __shfl_xor(s1, 4, 16); s2 += __shfl_xor(s2, 4, 16);
    s1 += __shfl_xor(s1, 8, 16); s2 += __shfl_xor(s2, 8, 16);
    if (r == 0) {
        float mu = s1 * (1.f / 128.f);
        float var = s2 * (1.f / 128.f) - mu * mu;
        s_mu[g] = mu;
        s_rs[g] = rsqrtf(var + 1e-5f);
    }
    __syncthreads();

    const float gmj = gamma[j], btj = beta[j];
#pragma unroll
    for (int a = 0; a < 8; ++a) {
        int aa = half * 8 + a;
        float x = s_res[aa * 128 + j];
        out[base + aa * 128 + j] = (x - s_mu[aa]) * s_rs[aa] * gmj + btj;
    }
}

// ---------------------------------------------------------------------------
extern "C" void kernel_launch(void* const* d_in, const int* in_sizes, int n_in,
                              void* d_out, int out_size, void* d_ws, size_t ws_size,
                              hipStream_t stream) {
    const float* atom_fea = (const float*)d_in[0];
    const float* nbr_fea  = (const float*)d_in[1];
    const int*   nbr_idx  = (const int*)d_in[2];
    const float* Wq = (const float*)d_in[3];
    const float* bq = (const float*)d_in[4];
    const float* Wk = (const float*)d_in[5];
    const float* bk = (const float*)d_in[6];
    const float* Wv = (const float*)d_in[7];
    const float* bv = (const float*)d_in[8];
    const float* Wn = (const float*)d_in[9];
    const float* bn = (const float*)d_in[10];
    const float* Wo = (const float*)d_in[11];
    const float* bo = (const float*)d_in[12];
    const float* Wg = (const float*)d_in[13];
    const float* bg = (const float*)d_in[14];
    const float* gm = (const float*)d_in[15];
    const float* bt = (const float*)d_in[16];

    float* qbuf = (float*)d_ws;                       // [N,128] -> becomes att
    float* kbuf = qbuf + (size_t)NATOM * FDIM;
    float* vbuf = kbuf + (size_t)NATOM * FDIM;
    short* pk1  = (short*)(vbuf + (size_t)NATOM * FDIM);  // 49152 bf16
    short* pk2  = pk1 + 49152;                            // 8192 bf16
    float* outp = (float*)d_out;

    pack_weights<<<224, 256, 0, stream>>>(Wq, Wk, Wv, Wn, pk1, pk2);
    qkv_mfma<<<(NATOM + 63) / 64, 256, 0, stream>>>(
        atom_fea, pk1, bq, bk, bv, qbuf, kbuf, vbuf);
    attn_mfma<<<NATOM / 8, 256, 0, stream>>>(
        nbr_fea, nbr_idx, pk2, bn, qbuf, kbuf, vbuf);
    out_kernel<<<NATOM / 16, 256, 0, stream>>>(
        qbuf, atom_fea, Wo, bo, Wg, bg, gm, bt, outp);
}

// Round 3
// 714.161 us; speedup vs baseline: 1.7208x; 1.7208x over previous
//
#include <hip/hip_runtime.h>
#include <math.h>

#define NATOM 100000
#define MNBR 12
#define FDIM 128
#define NFDIM 64

typedef __attribute__((ext_vector_type(8))) short bf16x8;
typedef __attribute__((ext_vector_type(4))) float f32x4;

__device__ inline unsigned short f2bf(float x) {
    union { float f; unsigned u; } v; v.f = x;
    unsigned r = v.u + 0x7FFFu + ((v.u >> 16) & 1u);   // RNE
    return (unsigned short)(r >> 16);
}

__device__ inline void st4bf(short* p, float4 x) {
    unsigned lo = (unsigned)f2bf(x.x) | ((unsigned)f2bf(x.y) << 16);
    unsigned hi = (unsigned)f2bf(x.z) | ((unsigned)f2bf(x.w) << 16);
    *(uint2*)p = make_uint2(lo, hi);
}

// ---------------------------------------------------------------------------
// K0: pack Wq|Wk|Wv -> pk1, Wn -> pk2, Wo -> pk3 in bf16 B-fragment order.
// B-frag (16x16x32): lane holds B[k=(lane>>4)*8+j][n=lane&15], j=0..7.
// short index = ((fragId*ksteps + s)*64 + lane)*8 + j.
// ---------------------------------------------------------------------------
__global__ __launch_bounds__(256) void pack_weights(
    const float* __restrict__ Wq, const float* __restrict__ Wk,
    const float* __restrict__ Wv, const float* __restrict__ Wn,
    const float* __restrict__ Wo,
    short* __restrict__ pk1, short* __restrict__ pk2, short* __restrict__ pk3)
{
    int g = blockIdx.x * 256 + threadIdx.x;
    if (g < 49152) {                       // Wq|Wk|Wv: 24 frags x 4 ksteps
        int fe = g >> 9;                   // f*4 + s
        int r = g & 511;
        int lane = r >> 3, jj = r & 7;
        int s = fe & 3, f = fe >> 2;
        int ct = f & 7, mt = f >> 3;
        int k = s * 32 + (lane >> 4) * 8 + jj;
        int n = ct * 16 + (lane & 15);
        const float* W = (mt == 0) ? Wq : ((mt == 1) ? Wk : Wv);
        pk1[g] = (short)f2bf(W[k * 128 + n]);
    } else if (g < 57344) {                // Wn: 8 frags x 2 ksteps
        int g2 = g - 49152;
        int fe = g2 >> 9;                  // ct*2 + s
        int r = g2 & 511;
        int lane = r >> 3, jj = r & 7;
        int s = fe & 1, ct = fe >> 1;
        int k = s * 32 + (lane >> 4) * 8 + jj;
        int n = ct * 16 + (lane & 15);
        pk2[g2] = (short)f2bf(Wn[k * 128 + n]);
    } else {                               // Wo: 8 frags x 4 ksteps
        int g3 = g - 57344;
        int fe = g3 >> 9;                  // f*4 + s
        int r = g3 & 511;
        int lane = r >> 3, jj = r & 7;
        int s = fe & 3, ct = fe >> 2;
        int k = s * 32 + (lane >> 4) * 8 + jj;
        int n = ct * 16 + (lane & 15);
        pk3[g3] = (short)f2bf(Wo[k * 128 + n]);
    }
}

// ---------------------------------------------------------------------------
// K1: QKV via MFMA. 128 atoms/block. Wave w owns col-tiles {6w..6w+5} of 24
// (q|k|v x 8), loops over 8 row-tiles. acc = 6 f32x4 (24 VGPRs) per row-tile;
// 6 batched B-frag loads per k-step (ILP, no register blowup).
// ---------------------------------------------------------------------------
__global__ __launch_bounds__(256) void qkv_mfma(
    const float* __restrict__ atom_fea,
    const short* __restrict__ pk1,
    const float* __restrict__ bq, const float* __restrict__ bk,
    const float* __restrict__ bv,
    float* __restrict__ q, float* __restrict__ k, float* __restrict__ v)
{
    __shared__ short s_a[128 * 136];   // 34816 B
    const int tid = threadIdx.x;
    const int base = blockIdx.x * 128;
#pragma unroll
    for (int e = 0; e < 16; ++e) {
        int f4 = e * 256 + tid;            // float4 index in 128x128 tile
        int row = f4 >> 5, c4 = f4 & 31;
        int atom = base + row;
        float4 x = make_float4(0.f, 0.f, 0.f, 0.f);
        if (atom < NATOM) x = *(const float4*)(atom_fea + (size_t)atom * 128 + c4 * 4);
        st4bf(&s_a[row * 136 + c4 * 4], x);
    }
    __syncthreads();

    const int lane = tid & 63, w = tid >> 6;
    const int quad = lane >> 4, j16 = lane & 15;

    for (int rt = 0; rt < 8; ++rt) {
        f32x4 acc[6];
#pragma unroll
        for (int fl = 0; fl < 6; ++fl) acc[fl] = (f32x4){0.f, 0.f, 0.f, 0.f};

        const short* arow = &s_a[(rt * 16 + j16) * 136];
#pragma unroll
        for (int s = 0; s < 4; ++s) {
            bf16x8 af = *(const bf16x8*)(arow + s * 32 + quad * 8);
            bf16x8 bfr[6];
#pragma unroll
            for (int fl = 0; fl < 6; ++fl)
                bfr[fl] = *(const bf16x8*)(pk1 + ((((w * 6 + fl) * 4 + s) * 64 + lane) << 3));
#pragma unroll
            for (int fl = 0; fl < 6; ++fl)
                acc[fl] = __builtin_amdgcn_mfma_f32_16x16x32_bf16(af, bfr[fl], acc[fl], 0, 0, 0);
        }
#pragma unroll
        for (int fl = 0; fl < 6; ++fl) {
            const int f = w * 6 + fl;
            const int mt = f >> 3, ct = f & 7;
            const int col = ct * 16 + j16;
            const float b = (mt == 0 ? bq : (mt == 1 ? bk : bv))[col];
            float* op = (mt == 0 ? q : (mt == 1 ? k : v));
#pragma unroll
            for (int r = 0; r < 4; ++r) {
                int atom = base + rt * 16 + quad * 4 + r;
                if (atom < NATOM) op[(size_t)atom * 128 + col] = acc[fl][r] + b;
            }
        }
    }
}

// ---------------------------------------------------------------------------
// K2: fused neighbor projection (MFMA) + gather + attention.
// 8 atoms/block. Neighbor m -> LDS row (m/3)*4 + (m%3): every quad gets
// 3 valid rows + 1 zero pad row (reg 3), balancing the gather across lanes.
// Per-atom interleave: 4 MFMAs then epilogue (only 8 acc VGPRs live).
// att overwrites the q buffer.
// ---------------------------------------------------------------------------
__global__ __launch_bounds__(256) void attn_mfma(
    const float* __restrict__ nbr_fea,
    const int*   __restrict__ nbr_idx,
    const short* __restrict__ pk2,
    const float* __restrict__ bn,
    float* qatt,
    const float* __restrict__ kbuf,
    const float* __restrict__ vbuf)
{
    __shared__ short s_a[8 * 16 * 72];   // 18432 B
    const int tid = threadIdx.x;
    const long long blk = blockIdx.x;

    const float* gsrc = nbr_fea + blk * 6144;
#pragma unroll
    for (int e = 0; e < 6; ++e) {
        int f4 = e * 256 + tid;            // [0,1536): 96 rows x 16 float4
        int r = f4 >> 4, c4 = f4 & 15;
        int a = r / 12, m = r - a * 12;
        int lrow = (m / 3) * 4 + (m % 3);  // balanced pad layout
        float4 x = *(const float4*)(gsrc + (size_t)f4 * 4);
        st4bf(&s_a[(a * 16 + lrow) * 72 + c4 * 4], x);
    }
    {   // zero pad rows r=3 of each quad: 8 atoms x 4 rows x 128 B
        int prow = tid >> 3, c = tid & 7;
        int a = prow >> 2, qd = prow & 3;
        *(uint4*)&s_a[(a * 16 + qd * 4 + 3) * 72 + c * 8] = make_uint4(0, 0, 0, 0);
    }
    __syncthreads();

    const int lane = tid & 63, w = tid >> 6;
    const int quad = lane >> 4, j16 = lane & 15;

    bf16x8 bfr[2][2];                      // [hh][kstep]
#pragma unroll
    for (int hh = 0; hh < 2; ++hh)
#pragma unroll
        for (int s = 0; s < 2; ++s) {
            int ct = w * 2 + hh;
            bfr[hh][s] = *(const bf16x8*)(pk2 + (((ct * 2 + s) * 64 + lane) << 3));
        }

    const float bnc0 = bn[w * 32 + j16];
    const float bnc1 = bn[w * 32 + 16 + j16];

#pragma unroll
    for (int a = 0; a < 8; ++a) {
        const long long n = blk * 8 + a;
        f32x4 acc0 = (f32x4){0.f, 0.f, 0.f, 0.f};
        f32x4 acc1 = (f32x4){0.f, 0.f, 0.f, 0.f};
#pragma unroll
        for (int s = 0; s < 2; ++s) {
            bf16x8 af = *(const bf16x8*)&s_a[(a * 16 + j16) * 72 + s * 32 + quad * 8];
            acc0 = __builtin_amdgcn_mfma_f32_16x16x32_bf16(af, bfr[0][s], acc0, 0, 0, 0);
            acc1 = __builtin_amdgcn_mfma_f32_16x16x32_bf16(af, bfr[1][s], acc1, 0, 0, 0);
        }
        int nidx[3];
#pragma unroll
        for (int r = 0; r < 3; ++r)
            nidx[r] = nbr_idx[n * 12 + quad * 3 + r];

#pragma unroll
        for (int hh = 0; hh < 2; ++hh) {
            const int col = w * 32 + hh * 16 + j16;
            const float bnc = hh ? bnc1 : bnc0;
            const f32x4 t = hh ? acc1 : acc0;
            const float qv = qatt[n * 128 + col];
            float sc[3], nv[3];
#pragma unroll
            for (int r = 0; r < 3; ++r) {
                float tm = t[r] + bnc;                 // nbr_t + bn
                size_t off = (size_t)nidx[r] * 128 + col;
                float nk = kbuf[off] + tm;
                nv[r] = vbuf[off] + tm;
                float p = qv * nk;
                p += __shfl_xor(p, 1, 16);
                p += __shfl_xor(p, 2, 16);
                p += __shfl_xor(p, 4, 16);
                p += __shfl_xor(p, 8, 16);
                sc[r] = p * 0.25f;                     // 1/sqrt(16)
            }
            float mx = fmaxf(fmaxf(sc[0], sc[1]), sc[2]);
            mx = fmaxf(mx, __shfl_xor(mx, 16));
            mx = fmaxf(mx, __shfl_xor(mx, 32));
            float es = 0.f, av = 0.f;
#pragma unroll
            for (int r = 0; r < 3; ++r) {
                float e = __expf(sc[r] - mx);
                es += e;
                av += e * nv[r];
            }
            es += __shfl_xor(es, 16); es += __shfl_xor(es, 32);
            av += __shfl_xor(av, 16); av += __shfl_xor(av, 32);
            if (quad == 0) qatt[n * 128 + col] = av / es;
        }
    }
}

// ---------------------------------------------------------------------------
// K3: out projection (MFMA) + sigmoid gate + residual + LayerNorm.
// 64 atoms/block; wave w = row-tile w. Gate/LN register-resident via
// width-16 shuffle groups (group g handles atoms {g, g+16, g+32, g+48}).
// ---------------------------------------------------------------------------
__global__ __launch_bounds__(256) void out_mfma(
    const float* __restrict__ attb, const float* __restrict__ atom_fea,
    const short* __restrict__ pk3, const float* __restrict__ bo,
    const float* __restrict__ Wg, const float* __restrict__ bg,
    const float* __restrict__ gamma, const float* __restrict__ beta,
    float* __restrict__ out)
{
    __shared__ short s_a[64 * 136];    // 17408 B (att tile, bf16)
    __shared__ float s_o[64 * 132];    // 33792 B (out tile, fp32)
    const int tid = threadIdx.x;
    const int base = blockIdx.x * 64;
#pragma unroll
    for (int e = 0; e < 8; ++e) {
        int f4 = e * 256 + tid;            // 64 rows x 32 float4
        int row = f4 >> 5, c4 = f4 & 31;
        int atom = base + row;
        float4 x = make_float4(0.f, 0.f, 0.f, 0.f);
        if (atom < NATOM) x = *(const float4*)(attb + (size_t)atom * 128 + c4 * 4);
        st4bf(&s_a[row * 136 + c4 * 4], x);
    }
    __syncthreads();

    const int lane = tid & 63, w = tid >> 6;
    const int quad = lane >> 4, j16 = lane & 15;

    f32x4 acc[8];
#pragma unroll
    for (int f = 0; f < 8; ++f) acc[f] = (f32x4){0.f, 0.f, 0.f, 0.f};

    const short* arow = &s_a[(w * 16 + j16) * 136];
#pragma unroll
    for (int s = 0; s < 4; ++s) {
        bf16x8 af = *(const bf16x8*)(arow + s * 32 + quad * 8);
        bf16x8 bfr[8];
#pragma unroll
        for (int f = 0; f < 8; ++f)
            bfr[f] = *(const bf16x8*)(pk3 + (((f * 4 + s) * 64 + lane) << 3));
#pragma unroll
        for (int f = 0; f < 8; ++f)
            acc[f] = __builtin_amdgcn_mfma_f32_16x16x32_bf16(af, bfr[f], acc[f], 0, 0, 0);
    }
#pragma unroll
    for (int f = 0; f < 8; ++f) {
        const int col = f * 16 + j16;
        const float b = bo[col];
#pragma unroll
        for (int r = 0; r < 4; ++r)
            s_o[(w * 16 + quad * 4 + r) * 132 + col] = acc[f][r] + b;
    }
    __syncthreads();

    // gate + LN: group g (16 lanes) handles atoms {g, g+16, g+32, g+48}
    const int g = tid >> 4;
    const int r16 = tid & 15;
    for (int p = 0; p < 4; ++p) {
        const int a_loc = p * 16 + g;
        const int atom = base + a_loc;
        const bool ok = (atom < NATOM);
        float o8[8], res8[8];
        float pg = 0.f;
#pragma unroll
        for (int tt = 0; tt < 8; ++tt) {
            int jj = r16 + tt * 16;
            o8[tt] = s_o[a_loc * 132 + jj];
            res8[tt] = ok ? atom_fea[(size_t)atom * 128 + jj] : 0.f;
            pg += o8[tt] * Wg[jj] + res8[tt] * Wg[128 + jj];
        }
        pg += __shfl_xor(pg, 1, 16);
        pg += __shfl_xor(pg, 2, 16);
        pg += __shfl_xor(pg, 4, 16);
        pg += __shfl_xor(pg, 8, 16);
        const float gt = 1.f / (1.f + __expf(-(pg + bg[0])));

        float s1 = 0.f, s2 = 0.f;
        float gv8[8];
#pragma unroll
        for (int tt = 0; tt < 8; ++tt) {
            float gv = gt * o8[tt] + (1.f - gt) * res8[tt];
            gv8[tt] = gv;
            s1 += gv; s2 += gv * gv;
        }
        s1 += __shfl_xor(s1, 1, 16); s2 += __shfl_xor(s2, 1, 16);
        s1 += __shfl_xor(s1, 2, 16); s2 += __shfl_xor(s2, 2, 16);
        s1 += __shfl_xor(s1, 4, 16); s2 += __shfl_xor(s2, 4, 16);
        s1 += __shfl_xor(s1, 8, 16); s2 += __shfl_xor(s2, 8, 16);
        const float mu = s1 * (1.f / 128.f);
        const float var = s2 * (1.f / 128.f) - mu * mu;
        const float rs = rsqrtf(var + 1e-5f);
        if (ok) {
#pragma unroll
            for (int tt = 0; tt < 8; ++tt) {
                int jj = r16 + tt * 16;
                out[(size_t)atom * 128 + jj] =
                    (gv8[tt] - mu) * rs * gamma[jj] + beta[jj];
            }
        }
    }
}

// ---------------------------------------------------------------------------
extern "C" void kernel_launch(void* const* d_in, const int* in_sizes, int n_in,
                              void* d_out, int out_size, void* d_ws, size_t ws_size,
                              hipStream_t stream) {
    const float* atom_fea = (const float*)d_in[0];
    const float* nbr_fea  = (const float*)d_in[1];
    const int*   nbr_idx  = (const int*)d_in[2];
    const float* Wq = (const float*)d_in[3];
    const float* bq = (const float*)d_in[4];
    const float* Wk = (const float*)d_in[5];
    const float* bk = (const float*)d_in[6];
    const float* Wv = (const float*)d_in[7];
    const float* bv = (const float*)d_in[8];
    const float* Wn = (const float*)d_in[9];
    const float* bn = (const float*)d_in[10];
    const float* Wo = (const float*)d_in[11];
    const float* bo = (const float*)d_in[12];
    const float* Wg = (const float*)d_in[13];
    const float* bg = (const float*)d_in[14];
    const float* gm = (const float*)d_in[15];
    const float* bt = (const float*)d_in[16];

    float* qbuf = (float*)d_ws;                       // [N,128] -> becomes att
    float* kbuf = qbuf + (size_t)NATOM * FDIM;
    float* vbuf = kbuf + (size_t)NATOM * FDIM;
    short* pk1  = (short*)(vbuf + (size_t)NATOM * FDIM);  // 49152 bf16
    short* pk2  = pk1 + 49152;                            // 8192 bf16
    short* pk3  = pk2 + 8192;                             // 16384 bf16
    float* outp = (float*)d_out;

    pack_weights<<<288, 256, 0, stream>>>(Wq, Wk, Wv, Wn, Wo, pk1, pk2, pk3);
    qkv_mfma<<<(NATOM + 127) / 128, 256, 0, stream>>>(
        atom_fea, pk1, bq, bk, bv, qbuf, kbuf, vbuf);
    attn_mfma<<<NATOM / 8, 256, 0, stream>>>(
        nbr_fea, nbr_idx, pk2, bn, qbuf, kbuf, vbuf);
    out_mfma<<<(NATOM + 63) / 64, 256, 0, stream>>>(
        qbuf, atom_fea, pk3, bo, Wg, bg, gm, bt, outp);
}